// Round 2
// baseline (17248.865 us; speedup 1.0000x reference)
//
#include <hip/hip_runtime.h>

#define B_ 64
#define TT 1024
#define HH 256

__device__ __forceinline__ float sigmoidf_(float x) { return 1.f / (1.f + __expf(-x)); }

// ---------------------------------------------------------------------------
// xgemm: out[M'][1024] = A'[M'][K] @ W[1024][K]^T + (bih+bhh)
// A' row m -> (b = m>>LC, tc = m&(CHUNK-1)), global row = A + (b*RINGA + slot)*K,
// slot = s0A + tc (one conditional wrap). Tile 128x128, 256 thr, 8x8/thread.
// ---------------------------------------------------------------------------
__global__ __launch_bounds__(256) void xgemm_kernel(
    const float* __restrict__ A, const float* __restrict__ W,
    const float* __restrict__ bih, const float* __restrict__ bhh,
    float* __restrict__ out,
    int K, int RINGA, int s0A, int LC)
{
    __shared__ float As[16][132];
    __shared__ float Bs[16][132];
    const int tid = threadIdx.x;
    const int bm = (int)blockIdx.x >> 3;
    const int bn = (int)blockIdx.x & 7;
    const int m0 = bm << 7, n0 = bn << 7;
    const int ty = tid >> 4, tx = tid & 15;
    const int CM = (1 << LC) - 1;

    const float* arow[8];
    const float* brow[8];
#pragma unroll
    for (int i = 0; i < 8; ++i) {
        int mm = m0 + i * 16 + ty;
        int bb = mm >> LC, tc = mm & CM;
        int slot = s0A + tc; if (slot >= RINGA) slot -= RINGA;
        arow[i] = A + ((size_t)bb * RINGA + slot) * K + tx;
        brow[i] = W + (size_t)(n0 + i * 16 + ty) * K + tx;
    }

    float acc[8][8];
#pragma unroll
    for (int i = 0; i < 8; ++i)
#pragma unroll
        for (int j = 0; j < 8; ++j) acc[i][j] = 0.f;

    for (int kc = 0; kc < K; kc += 16) {
#pragma unroll
        for (int i = 0; i < 8; ++i) {
            As[tx][i * 16 + ty] = arow[i][kc];
            Bs[tx][i * 16 + ty] = brow[i][kc];
        }
        __syncthreads();
#pragma unroll
        for (int k = 0; k < 16; ++k) {
            float a[8], bf[8];
#pragma unroll
            for (int j = 0; j < 8; ++j) a[j] = As[k][ty * 8 + j];
#pragma unroll
            for (int j = 0; j < 8; ++j) bf[j] = Bs[k][tx * 8 + j];
#pragma unroll
            for (int i = 0; i < 8; ++i)
#pragma unroll
                for (int j = 0; j < 8; ++j) acc[i][j] = fmaf(a[i], bf[j], acc[i][j]);
        }
        __syncthreads();
    }

    float bias[8];
#pragma unroll
    for (int j = 0; j < 8; ++j) bias[j] = bih[n0 + tx * 8 + j] + bhh[n0 + tx * 8 + j];
#pragma unroll
    for (int i = 0; i < 8; ++i) {
        float4 v0 = make_float4(acc[i][0] + bias[0], acc[i][1] + bias[1],
                                acc[i][2] + bias[2], acc[i][3] + bias[3]);
        float4 v1 = make_float4(acc[i][4] + bias[4], acc[i][5] + bias[5],
                                acc[i][6] + bias[6], acc[i][7] + bias[7]);
        size_t o = (size_t)(m0 + ty * 8 + i) * 1024 + n0 + tx * 8;
        *(float4*)&out[o] = v0;
        *(float4*)&out[o + 4] = v1;
    }
}

// ---------------------------------------------------------------------------
// Persistent-per-chunk recurrence. 256 WGs = 64 batch x 4 quads; WG owns 64
// hidden dims (256 gate rows x 256 cols of W_hh in registers, float4 w4[32]).
// Cross-quad h exchange via hring (agent-scope atomics through LLC) + monotone
// step-counter flags. blockIdx = b + 64q -> all quads of b on XCD b%8.
// State (c, h_prev) persisted in cstate / hring across chunk launches.
// ---------------------------------------------------------------------------
__global__ __launch_bounds__(512) void recur_chunk(
    const float* __restrict__ xg,    // [B][CHUNK][1024]
    const float* __restrict__ Whh,   // [1024][256]
    float* __restrict__ hring,       // [B][RING][256]
    float* __restrict__ cstate,      // [256][64]
    int* __restrict__ flags,         // [B][4]*32 ints
    int t0, int nsteps, int s0, int RING, int LC, int first)
{
    const int tid = threadIdx.x;
    const int b = (int)blockIdx.x & 63;
    const int q = (int)blockIdx.x >> 6;
    const int w = tid >> 6;          // wave 0..7
    const int l = tid & 63;
    const int hf = l >> 5;           // column half
    const int r = w * 32 + (l & 31); // local gate row 0..255
    const int gr = ((r >> 6) << 8) + (q << 6) + (r & 63); // global gate row

    __shared__ __align__(16) float sh_h[256];
    __shared__ float sh_gate[256];

    float4 w4[32];
    {
        const float4* src = (const float4*)(Whh + (size_t)gr * 256 + (hf << 7));
#pragma unroll
        for (int j = 0; j < 32; ++j) w4[j] = src[j];
    }

    float c = 0.f;
    if (!first && tid < 64) c = cstate[((int)blockIdx.x << 6) + tid];
    if (tid < 256) {
        if (first) {
            sh_h[tid] = 0.f;
        } else {
            int sprev = (s0 == 0) ? RING - 1 : s0 - 1;
            sh_h[tid] = hring[((size_t)b * RING + sprev) * HH + tid];
        }
    }
    int* myflag = flags + (((b << 2) + q) << 5);
    __syncthreads();

    const size_t hbB = (size_t)b * RING;

    for (int tc = 0; tc < nsteps; ++tc) {
        const int t = t0 + tc;
        int slot = s0 + tc; if (slot >= RING) slot -= RING;

        float xgv = 0.f;
        if (hf == 0) xgv = xg[((size_t)((b << LC) + tc) << 10) + gr];

        float acc = 0.f;
        const float4* h4 = ((const float4*)sh_h) + (hf << 5);
#pragma unroll
        for (int j = 0; j < 32; ++j) {
            float4 hv = h4[j], wv = w4[j];
            acc = fmaf(wv.x, hv.x, acc);
            acc = fmaf(wv.y, hv.y, acc);
            acc = fmaf(wv.z, hv.z, acc);
            acc = fmaf(wv.w, hv.w, acc);
        }
        acc += __shfl_xor(acc, 32);
        if (hf == 0) sh_gate[r] = acc + xgv;
        __syncthreads();

        if (tid < 64) {  // wave 0: gate update for our 64 hidden dims
            float gi = sh_gate[tid];
            float gf = sh_gate[64 + tid];
            float gg = sh_gate[128 + tid];
            float go = sh_gate[192 + tid];
            float i_ = sigmoidf_(gi);
            float f_ = sigmoidf_(gf);
            float g_ = tanhf(gg);
            float o_ = sigmoidf_(go);
            c = fmaf(f_, c, i_ * g_);
            float hn = o_ * tanhf(c);
            sh_h[(q << 6) + tid] = hn;
            __hip_atomic_store(&hring[(hbB + slot) * HH + (q << 6) + tid], hn,
                               __ATOMIC_RELAXED, __HIP_MEMORY_SCOPE_AGENT);
        }
        if (w == 0) {
            __builtin_amdgcn_fence(__ATOMIC_RELEASE, "agent");
            if (tid == 0)
                __hip_atomic_store(myflag, t + 1, __ATOMIC_RELAXED,
                                   __HIP_MEMORY_SCOPE_AGENT);
        }
        if (w >= 1 && w <= 3) {  // fetch one peer slice each
            const int p = (q + w) & 3;
            const int* pf = flags + (((b << 2) + p) << 5);
            while (__hip_atomic_load(pf, __ATOMIC_RELAXED,
                                     __HIP_MEMORY_SCOPE_AGENT) <= t) {
                __builtin_amdgcn_s_sleep(2);
            }
            __builtin_amdgcn_fence(__ATOMIC_ACQUIRE, "agent");
            sh_h[(p << 6) + l] =
                __hip_atomic_load(&hring[(hbB + slot) * HH + (p << 6) + l],
                                  __ATOMIC_RELAXED, __HIP_MEMORY_SCOPE_AGENT);
        }
        __syncthreads();
    }

    if (tid < 64) cstate[((int)blockIdx.x << 6) + tid] = c;
}

// ---------------------------------------------------------------------------
__global__ void fc_kernel(const float* __restrict__ h2r, int slot_last, int RING,
                          const float* __restrict__ fcw, const float* __restrict__ fcb,
                          float* __restrict__ out)
{
    int b = threadIdx.x;
    const float* h = h2r + ((size_t)b * RING + slot_last) * HH;
    float acc = 0.f;
    for (int d = 0; d < HH; ++d) acc = fmaf(h[d], fcw[d], acc);
    out[b] = acc + fcb[0];
}

extern "C" void kernel_launch(void* const* d_in, const int* in_sizes, int n_in,
                              void* d_out, int out_size, void* d_ws, size_t ws_size,
                              hipStream_t stream)
{
    const float* x     = (const float*)d_in[0];   // [64][1024][64]
    const float* W_ih0 = (const float*)d_in[1];   // [1024][64]
    const float* W_hh0 = (const float*)d_in[2];   // [1024][256]
    const float* b_ih0 = (const float*)d_in[3];
    const float* b_hh0 = (const float*)d_in[4];
    const float* W_ih1 = (const float*)d_in[5];   // [1024][256]
    const float* W_hh1 = (const float*)d_in[6];   // [1024][256]
    const float* b_ih1 = (const float*)d_in[7];
    const float* b_hh1 = (const float*)d_in[8];
    const float* fc_w  = (const float*)d_in[9];   // [1][256]
    const float* fc_b  = (const float*)d_in[10];  // [1]
    float* out = (float*)d_out;

    // Workspace-adaptive chunk size (deterministic: ws_size is constant).
    auto need = [](size_t CH) -> size_t {
        return (65536ull * CH              // xgc  [64][CH][1024] f32
              + 32768ull * (CH + 1)        // h1r+h2r rings [64][CH+1][256] f32
              + 32768ull) * 4              // cstate x2
              + 65536ull;                  // flags
    };
    int CHUNK = 32, LC = 5;
    if      (ws_size >= need(256)) { CHUNK = 256; LC = 8; }
    else if (ws_size >= need(128)) { CHUNK = 128; LC = 7; }
    else if (ws_size >= need(64))  { CHUNK = 64;  LC = 6; }
    const int RING = CHUNK + 1;

    float* ws  = (float*)d_ws;
    float* xgc = ws;                              // 65536*CHUNK
    float* h1r = xgc + 65536ull * CHUNK;          // 16384*RING
    float* h2r = h1r + 16384ull * RING;           // 16384*RING
    float* c0  = h2r + 16384ull * RING;           // 16384
    float* c1  = c0 + 16384;                      // 16384
    int* flags = (int*)(c1 + 16384);              // 16384 ints (2 layers x 8192)

    hipMemsetAsync(flags, 0, 16384 * sizeof(int), stream);

    const int nchunks = TT / CHUNK;
    const int gemmblk = (B_ * CHUNK / 128) * 8;

    for (int k = 0; k < nchunks; ++k) {
        const int t0 = k * CHUNK;
        const int s0 = t0 % RING;
        const int first = (k == 0) ? 1 : 0;

        // Layer 0: input GEMM (A = x, full [64][1024][64], no ring wrap)
        xgemm_kernel<<<dim3(gemmblk), dim3(256), 0, stream>>>(
            x, W_ih0, b_ih0, b_hh0, xgc, 64, TT, t0, LC);
        recur_chunk<<<dim3(256), dim3(512), 0, stream>>>(
            xgc, W_hh0, h1r, c0, flags, t0, CHUNK, s0, RING, LC, first);

        // Layer 1: input GEMM reads h1 ring chunk
        xgemm_kernel<<<dim3(gemmblk), dim3(256), 0, stream>>>(
            h1r, W_ih1, b_ih1, b_hh1, xgc, 256, RING, s0, LC);
        recur_chunk<<<dim3(256), dim3(512), 0, stream>>>(
            xgc, W_hh1, h2r, c1, flags + 8192, t0, CHUNK, s0, RING, LC, first);
    }

    const int slot_last = (TT - 1) % RING;
    fc_kernel<<<dim3(1), dim3(64), 0, stream>>>(h2r, slot_last, RING, fc_w, fc_b, out);
}

// Round 3
// 3575.310 us; speedup vs baseline: 4.8244x; 4.8244x over previous
//
#include <hip/hip_runtime.h>

#define B_ 64
#define TT 1024
#define HH 256

__device__ __forceinline__ float sigmoidf_(float x) { return 1.f / (1.f + __expf(-x)); }
__device__ __forceinline__ float fast_tanh(float x) {
    float e = __expf(2.f * x);
    return 1.f - 2.f / (e + 1.f);
}

// ---------------------------------------------------------------------------
// xgemm: out[M'][1024] = A'[M'][K] @ W[1024][K]^T + (bih+bhh)
// A' row m -> (b = m>>LC, tc = m&CM), element k at
//   A[((b*RINGA + slot)*K + k)*astr]   (astr=2 skips the tag lanes of hring).
// Tile 128x128, 256 threads, 8x8 outputs/thread.
// ---------------------------------------------------------------------------
__global__ __launch_bounds__(256) void xgemm_kernel(
    const float* __restrict__ A, const float* __restrict__ W,
    const float* __restrict__ bih, const float* __restrict__ bhh,
    float* __restrict__ out,
    int K, int RINGA, int s0A, int LC, int astr)
{
    __shared__ float As[16][132];
    __shared__ float Bs[16][132];
    const int tid = threadIdx.x;
    const int bm = (int)blockIdx.x >> 3;
    const int bn = (int)blockIdx.x & 7;
    const int m0 = bm << 7, n0 = bn << 7;
    const int ty = tid >> 4, tx = tid & 15;
    const int CM = (1 << LC) - 1;

    const float* arow[8];
    const float* brow[8];
#pragma unroll
    for (int i = 0; i < 8; ++i) {
        int mm = m0 + i * 16 + ty;
        int bb = mm >> LC, tc = mm & CM;
        int slot = s0A + tc; if (slot >= RINGA) slot -= RINGA;
        arow[i] = A + ((size_t)bb * RINGA + slot) * K * astr + tx * astr;
        brow[i] = W + (size_t)(n0 + i * 16 + ty) * K + tx;
    }

    float acc[8][8];
#pragma unroll
    for (int i = 0; i < 8; ++i)
#pragma unroll
        for (int j = 0; j < 8; ++j) acc[i][j] = 0.f;

    for (int kc = 0; kc < K; kc += 16) {
#pragma unroll
        for (int i = 0; i < 8; ++i) {
            As[tx][i * 16 + ty] = arow[i][kc * astr];
            Bs[tx][i * 16 + ty] = brow[i][kc];
        }
        __syncthreads();
#pragma unroll
        for (int k = 0; k < 16; ++k) {
            float a[8], bf[8];
#pragma unroll
            for (int j = 0; j < 8; ++j) a[j] = As[k][ty * 8 + j];
#pragma unroll
            for (int j = 0; j < 8; ++j) bf[j] = Bs[k][tx * 8 + j];
#pragma unroll
            for (int i = 0; i < 8; ++i)
#pragma unroll
                for (int j = 0; j < 8; ++j) acc[i][j] = fmaf(a[i], bf[j], acc[i][j]);
        }
        __syncthreads();
    }

    float bias[8];
#pragma unroll
    for (int j = 0; j < 8; ++j) bias[j] = bih[n0 + tx * 8 + j] + bhh[n0 + tx * 8 + j];
#pragma unroll
    for (int i = 0; i < 8; ++i) {
        float4 v0 = make_float4(acc[i][0] + bias[0], acc[i][1] + bias[1],
                                acc[i][2] + bias[2], acc[i][3] + bias[3]);
        float4 v1 = make_float4(acc[i][4] + bias[4], acc[i][5] + bias[5],
                                acc[i][6] + bias[6], acc[i][7] + bias[7]);
        size_t o = (size_t)(m0 + ty * 8 + i) * 1024 + n0 + tx * 8;
        *(float4*)&out[o] = v0;
        *(float4*)&out[o + 4] = v1;
    }
}

// ---------------------------------------------------------------------------
// Persistent-per-chunk recurrence. 256 WGs = 64 batch x 4 quads; WG owns 64
// hidden dims (256 gate rows x 256 cols of W_hh register-resident: float4
// w4[32] = 128 VGPR -> __launch_bounds__(512,2) to allow 256 VGPR/thread).
// Cross-quad exchange: each h element is ONE 8-byte word (tag<<32 | f32bits)
// stored with a relaxed agent-scope atomic (goes to LLC, correct across
// XCDs); consumers poll their own word until tag == t. No fences, no flags.
// Poison 0xAAAAAAAA never matches a tag (t < 1024). Ring slot for step t is
// written exactly once per launch with tag t, so no ABA.
// ---------------------------------------------------------------------------
__global__ __launch_bounds__(512, 2) void recur_chunk(
    const float* __restrict__ xg,             // [B][CHUNK][1024]
    const float* __restrict__ Whh,            // [1024][256]
    unsigned long long* __restrict__ hring,   // [B][RING][256] (tag,val) words
    float* __restrict__ cstate,               // [256][64]
    int t0, int nsteps, int s0, int RING, int LC, int first)
{
    const int tid = threadIdx.x;
    const int b = (int)blockIdx.x & 63;
    const int q = (int)blockIdx.x >> 6;
    const int w = tid >> 6;          // wave 0..7
    const int l = tid & 63;
    const int hf = l >> 5;           // column half
    const int r = w * 32 + (l & 31); // local gate row 0..255
    const int gr = ((r >> 6) << 8) + (q << 6) + (r & 63); // global gate row

    __shared__ __align__(16) float sh_h[256];
    __shared__ float sh_gate[256];

    float4 w4[32];
    {
        const float4* src = (const float4*)(Whh + (size_t)gr * 256 + (hf << 7));
#pragma unroll
        for (int j = 0; j < 32; ++j) w4[j] = src[j];
    }

    const size_t hbB = (size_t)b * RING;
    float c = 0.f;
    if (!first && tid < 64) c = cstate[((int)blockIdx.x << 6) + tid];
    if (tid < 256) {
        if (first) {
            sh_h[tid] = 0.f;
        } else {
            int sprev = (s0 == 0) ? RING - 1 : s0 - 1;
            unsigned long long v = hring[(hbB + sprev) * 256 + tid];
            sh_h[tid] = __uint_as_float((unsigned)v);
        }
    }
    __syncthreads();

    for (int tc = 0; tc < nsteps; ++tc) {
        const int t = t0 + tc;
        int slot = s0 + tc; if (slot >= RING) slot -= RING;
        const size_t srow = (hbB + slot) * 256;

        float xgv = 0.f;
        if (hf == 0) xgv = xg[((size_t)((b << LC) + tc) << 10) + gr];

        float acc = 0.f;
        const float4* h4 = ((const float4*)sh_h) + (hf << 5);
#pragma unroll
        for (int j = 0; j < 32; ++j) {
            float4 hv = h4[j], wv = w4[j];
            acc = fmaf(wv.x, hv.x, acc);
            acc = fmaf(wv.y, hv.y, acc);
            acc = fmaf(wv.z, hv.z, acc);
            acc = fmaf(wv.w, hv.w, acc);
        }
        acc += __shfl_xor(acc, 32);
        if (hf == 0) sh_gate[r] = acc + xgv;
        __syncthreads();

        if (tid < 64) {  // wave 0: gate update for our 64 hidden dims
            float gi = sh_gate[tid];
            float gf = sh_gate[64 + tid];
            float gg = sh_gate[128 + tid];
            float go = sh_gate[192 + tid];
            float i_ = sigmoidf_(gi);
            float f_ = sigmoidf_(gf);
            float g_ = fast_tanh(gg);
            float o_ = sigmoidf_(go);
            c = fmaf(f_, c, i_ * g_);
            float hn = o_ * fast_tanh(c);
            sh_h[(q << 6) + tid] = hn;
            unsigned long long word =
                ((unsigned long long)(unsigned)t << 32) | __float_as_uint(hn);
            __hip_atomic_store(&hring[srow + (q << 6) + tid], word,
                               __ATOMIC_RELAXED, __HIP_MEMORY_SCOPE_AGENT);
        } else if (w <= 3) {  // waves 1..3: fetch one peer slice each
            const int p = (q + w) & 3;
            unsigned long long* src = &hring[srow + (p << 6) + l];
            unsigned long long v;
            for (;;) {
                v = __hip_atomic_load(src, __ATOMIC_RELAXED,
                                      __HIP_MEMORY_SCOPE_AGENT);
                if ((int)(v >> 32) == t) break;
                __builtin_amdgcn_s_sleep(1);
            }
            sh_h[(p << 6) + l] = __uint_as_float((unsigned)v);
        }
        __syncthreads();
    }

    if (tid < 64) cstate[((int)blockIdx.x << 6) + tid] = c;
}

// ---------------------------------------------------------------------------
__global__ void fc_kernel(const unsigned long long* __restrict__ h2r,
                          int slot_last, int RING,
                          const float* __restrict__ fcw, const float* __restrict__ fcb,
                          float* __restrict__ out)
{
    int b = threadIdx.x;
    if (b < 64) {
        const unsigned long long* h = h2r + ((size_t)b * RING + slot_last) * 256;
        float acc = 0.f;
        for (int d = 0; d < HH; ++d)
            acc = fmaf(__uint_as_float((unsigned)h[d]), fcw[d], acc);
        out[b] = acc + fcb[0];
    }
}

extern "C" void kernel_launch(void* const* d_in, const int* in_sizes, int n_in,
                              void* d_out, int out_size, void* d_ws, size_t ws_size,
                              hipStream_t stream)
{
    const float* x     = (const float*)d_in[0];   // [64][1024][64]
    const float* W_ih0 = (const float*)d_in[1];   // [1024][64]
    const float* W_hh0 = (const float*)d_in[2];   // [1024][256]
    const float* b_ih0 = (const float*)d_in[3];
    const float* b_hh0 = (const float*)d_in[4];
    const float* W_ih1 = (const float*)d_in[5];   // [1024][256]
    const float* W_hh1 = (const float*)d_in[6];   // [1024][256]
    const float* b_ih1 = (const float*)d_in[7];
    const float* b_hh1 = (const float*)d_in[8];
    const float* fc_w  = (const float*)d_in[9];   // [1][256]
    const float* fc_b  = (const float*)d_in[10];  // [1]
    float* out = (float*)d_out;

    // Workspace-adaptive chunk size (deterministic across calls).
    auto need = [](size_t CH) -> size_t {
        return 4ull * (65536ull * CH            // xgc [64][CH][1024] f32
                     + 65536ull * (CH + 1)      // h1r+h2r rings, 8B words
                     + 32768ull);               // cstate x2
    };
    int CHUNK = 32, LC = 5;
    if      (ws_size >= need(256)) { CHUNK = 256; LC = 8; }
    else if (ws_size >= need(128)) { CHUNK = 128; LC = 7; }
    else if (ws_size >= need(64))  { CHUNK = 64;  LC = 6; }
    const int RING = CHUNK + 1;

    float* ws  = (float*)d_ws;
    float* xgc = ws;                                        // 65536*CHUNK f32
    unsigned long long* h1r =
        (unsigned long long*)(xgc + 65536ull * CHUNK);      // 16384*RING u64
    unsigned long long* h2r = h1r + 16384ull * RING;        // 16384*RING u64
    float* c0 = (float*)(h2r + 16384ull * RING);            // 16384 f32
    float* c1 = c0 + 16384;                                 // 16384 f32

    const int nchunks = TT / CHUNK;
    const int gemmblk = (B_ * CHUNK / 128) * 8;

    for (int k = 0; k < nchunks; ++k) {
        const int t0 = k * CHUNK;
        const int s0 = t0 % RING;
        const int first = (k == 0) ? 1 : 0;

        // Layer 0 input GEMM: A = x (plain f32, no ring, astr=1)
        xgemm_kernel<<<dim3(gemmblk), dim3(256), 0, stream>>>(
            x, W_ih0, b_ih0, b_hh0, xgc, 64, TT, t0, LC, 1);
        recur_chunk<<<dim3(256), dim3(512), 0, stream>>>(
            xgc, W_hh0, h1r, c0, t0, CHUNK, s0, RING, LC, first);

        // Layer 1 input GEMM: A = h1 ring (tagged pairs, astr=2)
        xgemm_kernel<<<dim3(gemmblk), dim3(256), 0, stream>>>(
            (const float*)h1r, W_ih1, b_ih1, b_hh1, xgc, 256, RING, s0, LC, 2);
        recur_chunk<<<dim3(256), dim3(512), 0, stream>>>(
            xgc, W_hh1, h2r, c1, t0, CHUNK, s0, RING, LC, first);
    }

    const int slot_last = (TT - 1) % RING;
    fc_kernel<<<dim3(1), dim3(64), 0, stream>>>(h2r, slot_last, RING, fc_w, fc_b, out);
}

// Round 4
// 3571.878 us; speedup vs baseline: 4.8291x; 1.0010x over previous
//
#include <hip/hip_runtime.h>

#define B_ 64
#define TT 1024
#define HH 256

__device__ __forceinline__ float sigmoidf_(float x) { return 1.f / (1.f + __expf(-x)); }
__device__ __forceinline__ float fast_tanh(float x) {
    float e = __expf(2.f * x);
    return 1.f - 2.f / (e + 1.f);
}

// ---------------------------------------------------------------------------
// xgemm: out[M'][1024] = A'[M'][K] @ W[1024][K]^T + (bih+bhh)
// A' row m -> (b = m>>LC, tc = m&CM), element k at
//   A[((b*RINGA + slot)*K + k)*astr]   (astr=2 skips the tag lanes of hring).
// Tile 128x128, 256 threads, 8x8 outputs/thread.
// ---------------------------------------------------------------------------
__global__ __launch_bounds__(256) void xgemm_kernel(
    const float* __restrict__ A, const float* __restrict__ W,
    const float* __restrict__ bih, const float* __restrict__ bhh,
    float* __restrict__ out,
    int K, int RINGA, int s0A, int LC, int astr)
{
    __shared__ float As[16][132];
    __shared__ float Bs[16][132];
    const int tid = threadIdx.x;
    const int bm = (int)blockIdx.x >> 3;
    const int bn = (int)blockIdx.x & 7;
    const int m0 = bm << 7, n0 = bn << 7;
    const int ty = tid >> 4, tx = tid & 15;
    const int CM = (1 << LC) - 1;

    const float* arow[8];
    const float* brow[8];
#pragma unroll
    for (int i = 0; i < 8; ++i) {
        int mm = m0 + i * 16 + ty;
        int bb = mm >> LC, tc = mm & CM;
        int slot = s0A + tc; if (slot >= RINGA) slot -= RINGA;
        arow[i] = A + ((size_t)bb * RINGA + slot) * K * astr + tx * astr;
        brow[i] = W + (size_t)(n0 + i * 16 + ty) * K + tx;
    }

    float acc[8][8];
#pragma unroll
    for (int i = 0; i < 8; ++i)
#pragma unroll
        for (int j = 0; j < 8; ++j) acc[i][j] = 0.f;

    for (int kc = 0; kc < K; kc += 16) {
#pragma unroll
        for (int i = 0; i < 8; ++i) {
            As[tx][i * 16 + ty] = arow[i][kc * astr];
            Bs[tx][i * 16 + ty] = brow[i][kc];
        }
        __syncthreads();
#pragma unroll
        for (int k = 0; k < 16; ++k) {
            float a[8], bf[8];
#pragma unroll
            for (int j = 0; j < 8; ++j) a[j] = As[k][ty * 8 + j];
#pragma unroll
            for (int j = 0; j < 8; ++j) bf[j] = Bs[k][tx * 8 + j];
#pragma unroll
            for (int i = 0; i < 8; ++i)
#pragma unroll
                for (int j = 0; j < 8; ++j) acc[i][j] = fmaf(a[i], bf[j], acc[i][j]);
        }
        __syncthreads();
    }

    float bias[8];
#pragma unroll
    for (int j = 0; j < 8; ++j) bias[j] = bih[n0 + tx * 8 + j] + bhh[n0 + tx * 8 + j];
#pragma unroll
    for (int i = 0; i < 8; ++i) {
        float4 v0 = make_float4(acc[i][0] + bias[0], acc[i][1] + bias[1],
                                acc[i][2] + bias[2], acc[i][3] + bias[3]);
        float4 v1 = make_float4(acc[i][4] + bias[4], acc[i][5] + bias[5],
                                acc[i][6] + bias[6], acc[i][7] + bias[7]);
        size_t o = (size_t)(m0 + ty * 8 + i) * 1024 + n0 + tx * 8;
        *(float4*)&out[o] = v0;
        *(float4*)&out[o + 4] = v1;
    }
}

// ---------------------------------------------------------------------------
// Persistent-per-chunk recurrence. 256 WGs = 64 batch x 4 quads; WG owns 64
// hidden dims = 256 gate rows x 256 cols of W_hh. 1024 threads: thread
// (r = tid>>2, c4 = tid&3) holds 64 weights (16 float4 = 64 VGPR). 16-wave
// block FORCES VGPR<=128 so weights stay register-resident (asm pin stops
// the allocator sinking the loads back into the loop).
// Cross-quad exchange: tagged 8-byte words (tag<<32 | f32bits) via relaxed
// agent-scope atomics through LLC; consumer polls its own word until tag==t.
// LDS h buffer padded +4 floats per 64-block: the 4 column-quarter bases hit
// banks {0-3},{4-7},{8-11},{12-15} -> conflict-free ds_read_b128.
// ---------------------------------------------------------------------------
__global__ __launch_bounds__(1024)
__attribute__((amdgpu_waves_per_eu(4, 4)))
void recur_chunk(
    const float* __restrict__ xg,             // [B][CHUNK][1024]
    const float* __restrict__ Whh,            // [1024][256]
    unsigned long long* __restrict__ hring,   // [B][RING][256] (tag,val) words
    float* __restrict__ cstate,               // [256][64]
    int t0, int nsteps, int s0, int RING, int LC, int first)
{
    const int tid = threadIdx.x;
    const int b = (int)blockIdx.x & 63;
    const int q = (int)blockIdx.x >> 6;
    const int w = tid >> 6;          // wave 0..15
    const int l = tid & 63;
    const int r = tid >> 2;          // local gate row 0..255
    const int c4 = tid & 3;          // column quarter
    const int gr = ((r >> 6) << 8) + (q << 6) + (r & 63); // global gate row

    __shared__ __align__(16) float sh_h[272];   // idx -> idx + (idx>>6)*4
    __shared__ float sh_gate[256];

    // 64 weight floats per thread, register-resident.
    float4 w4[16];
    {
        const float4* src = (const float4*)(Whh + (size_t)gr * 256 + (c4 << 6));
#pragma unroll
        for (int j = 0; j < 16; ++j) w4[j] = src[j];
    }
#pragma unroll
    for (int j = 0; j < 16; ++j)
        asm volatile("" : "+v"(w4[j].x), "+v"(w4[j].y), "+v"(w4[j].z), "+v"(w4[j].w));

    const size_t hbB = (size_t)b * RING;
    float c = 0.f;
    if (!first && tid < 64) c = cstate[((int)blockIdx.x << 6) + tid];
    if (tid < 272) sh_h[tid] = 0.f;
    if (!first && tid < 256) {
        int sprev = (s0 == 0) ? RING - 1 : s0 - 1;
        unsigned long long v = hring[(hbB + sprev) * 256 + tid];
        sh_h[tid + ((tid >> 6) << 2)] = __uint_as_float((unsigned)v);
    }
    __syncthreads();

    const float4* h4 = (const float4*)(sh_h + c4 * 68);

    for (int tc = 0; tc < nsteps; ++tc) {
        const int t = t0 + tc;
        int slot = s0 + tc; if (slot >= RING) slot -= RING;
        const size_t srow = (hbB + slot) * 256;

        float xgv = 0.f;
        if (c4 == 0) xgv = xg[((size_t)((b << LC) + tc) << 10) + gr];

        float acc = 0.f;
#pragma unroll
        for (int j = 0; j < 16; ++j) {
            float4 hv = h4[j], wv = w4[j];
            acc = fmaf(wv.x, hv.x, acc);
            acc = fmaf(wv.y, hv.y, acc);
            acc = fmaf(wv.z, hv.z, acc);
            acc = fmaf(wv.w, hv.w, acc);
        }
        acc += __shfl_xor(acc, 1);
        acc += __shfl_xor(acc, 2);
        if (c4 == 0) sh_gate[r] = acc + xgv;
        __syncthreads();

        if (w == 0) {  // wave 0: gate update for our 64 hidden dims
            float gi = sh_gate[l];
            float gf = sh_gate[64 + l];
            float gg = sh_gate[128 + l];
            float go = sh_gate[192 + l];
            float i_ = sigmoidf_(gi);
            float f_ = sigmoidf_(gf);
            float g_ = fast_tanh(gg);
            float o_ = sigmoidf_(go);
            c = fmaf(f_, c, i_ * g_);
            float hn = o_ * fast_tanh(c);
            sh_h[q * 68 + l] = hn;
            unsigned long long word =
                ((unsigned long long)(unsigned)t << 32) | __float_as_uint(hn);
            __hip_atomic_store(&hring[srow + (q << 6) + l], word,
                               __ATOMIC_RELAXED, __HIP_MEMORY_SCOPE_AGENT);
        } else if (w <= 3) {  // waves 1..3: fetch one peer slice each
            const int p = (q + w) & 3;
            unsigned long long* src = &hring[srow + (p << 6) + l];
            unsigned long long v;
            for (;;) {
                v = __hip_atomic_load(src, __ATOMIC_RELAXED,
                                      __HIP_MEMORY_SCOPE_AGENT);
                if ((int)(v >> 32) == t) break;
                __builtin_amdgcn_s_sleep(1);
            }
            sh_h[p * 68 + l] = __uint_as_float((unsigned)v);
        }
        __syncthreads();
    }

    if (tid < 64) cstate[((int)blockIdx.x << 6) + tid] = c;
}

// ---------------------------------------------------------------------------
__global__ void fc_kernel(const unsigned long long* __restrict__ h2r,
                          int slot_last, int RING,
                          const float* __restrict__ fcw, const float* __restrict__ fcb,
                          float* __restrict__ out)
{
    int b = threadIdx.x;
    if (b < 64) {
        const unsigned long long* h = h2r + ((size_t)b * RING + slot_last) * 256;
        float acc = 0.f;
        for (int d = 0; d < HH; ++d)
            acc = fmaf(__uint_as_float((unsigned)h[d]), fcw[d], acc);
        out[b] = acc + fcb[0];
    }
}

extern "C" void kernel_launch(void* const* d_in, const int* in_sizes, int n_in,
                              void* d_out, int out_size, void* d_ws, size_t ws_size,
                              hipStream_t stream)
{
    const float* x     = (const float*)d_in[0];   // [64][1024][64]
    const float* W_ih0 = (const float*)d_in[1];   // [1024][64]
    const float* W_hh0 = (const float*)d_in[2];   // [1024][256]
    const float* b_ih0 = (const float*)d_in[3];
    const float* b_hh0 = (const float*)d_in[4];
    const float* W_ih1 = (const float*)d_in[5];   // [1024][256]
    const float* W_hh1 = (const float*)d_in[6];   // [1024][256]
    const float* b_ih1 = (const float*)d_in[7];
    const float* b_hh1 = (const float*)d_in[8];
    const float* fc_w  = (const float*)d_in[9];   // [1][256]
    const float* fc_b  = (const float*)d_in[10];  // [1]
    float* out = (float*)d_out;

    // Workspace-adaptive chunk size (deterministic across calls).
    auto need = [](size_t CH) -> size_t {
        return 4ull * (65536ull * CH            // xgc [64][CH][1024] f32
                     + 65536ull * (CH + 1)      // h1r+h2r rings, 8B words
                     + 32768ull);               // cstate x2
    };
    int CHUNK = 32, LC = 5;
    if      (ws_size >= need(256)) { CHUNK = 256; LC = 8; }
    else if (ws_size >= need(128)) { CHUNK = 128; LC = 7; }
    else if (ws_size >= need(64))  { CHUNK = 64;  LC = 6; }
    const int RING = CHUNK + 1;

    float* ws  = (float*)d_ws;
    float* xgc = ws;                                        // 65536*CHUNK f32
    unsigned long long* h1r =
        (unsigned long long*)(xgc + 65536ull * CHUNK);      // 16384*RING u64
    unsigned long long* h2r = h1r + 16384ull * RING;        // 16384*RING u64
    float* c0 = (float*)(h2r + 16384ull * RING);            // 16384 f32
    float* c1 = c0 + 16384;                                 // 16384 f32

    const int nchunks = TT / CHUNK;
    const int gemmblk = (B_ * CHUNK / 128) * 8;

    for (int k = 0; k < nchunks; ++k) {
        const int t0 = k * CHUNK;
        const int s0 = t0 % RING;
        const int first = (k == 0) ? 1 : 0;

        // Layer 0 input GEMM: A = x (plain f32, no ring, astr=1)
        xgemm_kernel<<<dim3(gemmblk), dim3(256), 0, stream>>>(
            x, W_ih0, b_ih0, b_hh0, xgc, 64, TT, t0, LC, 1);
        recur_chunk<<<dim3(256), dim3(1024), 0, stream>>>(
            xgc, W_hh0, h1r, c0, t0, CHUNK, s0, RING, LC, first);

        // Layer 1 input GEMM: A = h1 ring (tagged pairs, astr=2)
        xgemm_kernel<<<dim3(gemmblk), dim3(256), 0, stream>>>(
            (const float*)h1r, W_ih1, b_ih1, b_hh1, xgc, 256, RING, s0, LC, 2);
        recur_chunk<<<dim3(256), dim3(1024), 0, stream>>>(
            xgc, W_hh1, h2r, c1, t0, CHUNK, s0, RING, LC, first);
    }

    const int slot_last = (TT - 1) % RING;
    fc_kernel<<<dim3(1), dim3(64), 0, stream>>>(h2r, slot_last, RING, fc_w, fc_b, out);
}